// Round 6
// baseline (951.242 us; speedup 1.0000x reference)
//
#include <hip/hip_runtime.h>
#include <hip/hip_bf16.h>
#include <math.h>

// TMSA R6: flash attention with K staged to LDS in fragment order (kt-loop has
// zero global loads) + __launch_bounds__(.,4) to force VGPR<=128 (4 waves/SIMD).
// Keeps R5's zero-shuffle S^T/P^T interleave, no-max softmax, packed V^T LDS,
// fc2 scatter-writes d_out, d2d X2 copy.
//
// ws (bytes), guard 110,100,480:
//   attn phase: Hb bf16 [0,31457280) | QKVc bf16 [31457280,78643200)
//               XOUTc bf16 [78643200,110100480)
//   mlp  phase: TMP fp32 [0,62914560) (d2d copy of X2) |
//               H2c bf16 [62914560,78643200) | HIDc bf16 [78643200,110100480)

typedef __attribute__((ext_vector_type(8))) short bf16x8;
typedef __attribute__((ext_vector_type(4))) float f32x4;

#define SCALE2 (0.22360679774997896f * 1.44269504088896340f)  // d^-0.5 * log2(e)
#define CHROWS 65536
#define QPLANE 7864320u   // 65536*120 elems per q/k/v plane (chunk)

union B8U { bf16x8 v; uint4 u4; uint2 u2[2]; unsigned u[4]; short s[8]; };

__device__ __forceinline__ short bf16b(float f) {
    __hip_bfloat16 h = __float2bfloat16(f);
    return *reinterpret_cast<short*>(&h);
}
__device__ __forceinline__ float bf2f(short s) {
    return __uint_as_float(((unsigned)(unsigned short)s) << 16);
}
__device__ __forceinline__ unsigned packbf(float a, float b) {
    return (unsigned)(unsigned short)bf16b(a) |
           ((unsigned)(unsigned short)bf16b(b) << 16);
}

// partitioned row r -> global row g
__device__ __forceinline__ int rev_row(int r) {
    int w = r >> 8, t = r & 255;
    int w8 = w & 7, h8 = (w >> 3) & 7, d2 = (w >> 6) & 1, n2 = w >> 7;
    int www = t & 7, hh = (t >> 3) & 7, dd = (t >> 6) & 1, nn = t >> 7;
    int n = n2 * 2 + nn, d = d2 * 2 + dd;
    int Hc = h8 * 8 + hh, Wc = w8 * 8 + www;
    return ((n * 4 + d) << 12) + (Hc << 6) + Wc;
}
// global row g -> partitioned row
__device__ __forceinline__ int part_row(int g) {
    int ww = g & 63, hh = (g >> 6) & 63, d = (g >> 12) & 3, n = g >> 14;
    int w = ((n >> 1) * 2 + (d >> 1)) * 64 + ((hh >> 3) << 3) + (ww >> 3);
    int t = (((n & 1) * 2 + (d & 1)) << 6) + ((hh & 7) << 3) + (ww & 7);
    return (w << 8) + t;
}
__device__ __forceinline__ float gelu_exact(float x) {
    return 0.5f * x * (1.0f + erff(x * 0.70710678118654752f));
}

// load B-frag from a 20-elem bf16 row (stride 20), k = quad*8..+7, zero-padded.
__device__ __forceinline__ bf16x8 load_frag20(const short* row, int quad) {
    B8U r;
    const uint2* p = (const uint2*)(row + quad * 8);
    r.u2[0] = p[0]; r.u2[1] = p[1];
    if (quad == 2) { r.u[2] = 0; r.u[3] = 0; }
    else if (quad == 3) { r.u[0] = r.u[1] = r.u[2] = r.u[3] = 0; }
    return r.v;
}

// ---------------- LayerNorm (C=120) fp32 in -> bf16 out ---------------------
template <bool REMAP>
__global__ __launch_bounds__(256) void ln_kernel(const float* __restrict__ in,
                                                 const float* __restrict__ w,
                                                 const float* __restrict__ b,
                                                 short* __restrict__ out) {
    int row  = blockIdx.x * 4 + (threadIdx.x >> 6);
    int lane = threadIdx.x & 63;
    const float* xr = in + (size_t)row * 120;
    float2 v = make_float2(0.f, 0.f);
    if (lane < 60) v = *(const float2*)(xr + lane * 2);
    float s = v.x + v.y;
#pragma unroll
    for (int off = 32; off; off >>= 1) s += __shfl_down(s, off, 64);
    s = __shfl(s, 0, 64);
    float mean = s * (1.f / 120.f);
    float dx = v.x - mean, dy = v.y - mean;
    float q = (lane < 60) ? (dx * dx + dy * dy) : 0.f;
#pragma unroll
    for (int off = 32; off; off >>= 1) q += __shfl_down(q, off, 64);
    q = __shfl(q, 0, 64);
    float rstd = rsqrtf(q * (1.f / 120.f) + 1e-5f);
    int orow = REMAP ? part_row(row) : row;
    if (lane < 60) {
        float2 wv = *(const float2*)(w + lane * 2);
        float2 bv = *(const float2*)(b + lane * 2);
        unsigned u = packbf(dx * rstd * wv.x + bv.x, dy * rstd * wv.y + bv.y);
        *(unsigned*)(out + (size_t)orow * 120 + lane * 2) = u;
    }
}

// ------------- MFMA GEMM: out = A(M x K, bf16) @ W(N x K, fp32)^T + bias ----
// MODE: 0 QKV scatter (q pre-scaled by SCALE2) | 1 proj(+x res -> X2 fp32)
//       2 gelu bf16 | 3 multiply-into bf16 | 4 fc2(+TMP res -> d_out @rev_row)
template <int MODE, int K, int N>
__global__ __launch_bounds__(256) void mm(const short* __restrict__ A,
                                          const float* __restrict__ W,
                                          const float* __restrict__ bias,
                                          void* __restrict__ outp,
                                          const float* __restrict__ aux,
                                          int m0) {
    const int lane = threadIdx.x & 63, wave = threadIdx.x >> 6;
    const int quad = lane >> 4, l16 = lane & 15;
    const int bm = blockIdx.x * 128 + (wave >> 1) * 64;
    const int bn = blockIdx.y * 64 + (wave & 1) * 32;

    f32x4 acc[4][2];
#pragma unroll
    for (int i = 0; i < 4; ++i)
#pragma unroll
        for (int j = 0; j < 2; ++j) acc[i][j] = (f32x4){0.f, 0.f, 0.f, 0.f};

    const short* Ar[4];
#pragma unroll
    for (int i = 0; i < 4; ++i) Ar[i] = A + (size_t)(bm + i * 16 + l16) * K;
    const int n0 = bn + l16, n1 = bn + 16 + l16;
    const int nc0 = n0 < N ? n0 : N - 1;
    const int nc1 = n1 < N ? n1 : N - 1;
    const float* W0 = W + (size_t)nc0 * K;
    const float* W1 = W + (size_t)nc1 * K;

    const int KT = (K + 31) / 32;
#pragma unroll
    for (int kt = 0; kt < KT; ++kt) {
        int kk = kt * 32 + quad * 8;
        bool kok = kk < K;
        int kc = kok ? kk : 0;
        bf16x8 a[4], b0v, b1v;
#pragma unroll
        for (int i = 0; i < 4; ++i) a[i] = *(const bf16x8*)(Ar[i] + kc);
        {
            f32x4 w0 = *(const f32x4*)(W0 + kc);
            f32x4 w1 = *(const f32x4*)(W0 + kc + 4);
            b0v = (bf16x8){bf16b(w0.x), bf16b(w0.y), bf16b(w0.z), bf16b(w0.w),
                           bf16b(w1.x), bf16b(w1.y), bf16b(w1.z), bf16b(w1.w)};
            f32x4 w2 = *(const f32x4*)(W1 + kc);
            f32x4 w3 = *(const f32x4*)(W1 + kc + 4);
            b1v = (bf16x8){bf16b(w2.x), bf16b(w2.y), bf16b(w2.z), bf16b(w2.w),
                           bf16b(w3.x), bf16b(w3.y), bf16b(w3.z), bf16b(w3.w)};
        }
        if (!kok) {
            bf16x8 zz = {0, 0, 0, 0, 0, 0, 0, 0};
            a[0] = a[1] = a[2] = a[3] = b0v = b1v = zz;
        }
#pragma unroll
        for (int i = 0; i < 4; ++i) {
            acc[i][0] = __builtin_amdgcn_mfma_f32_16x16x32_bf16(a[i], b0v, acc[i][0], 0, 0, 0);
            acc[i][1] = __builtin_amdgcn_mfma_f32_16x16x32_bf16(a[i], b1v, acc[i][1], 0, 0, 0);
        }
    }

#pragma unroll
    for (int j = 0; j < 2; ++j) {
        const int n = j ? n1 : n0;
        if (n >= N) continue;
        const float bs = bias[n];
        int which = 0, head = 0, e = 0;
        if (MODE == 0) { which = n / 120; int hn = n % 120; head = hn / 20; e = hn % 20; }
#pragma unroll
        for (int i = 0; i < 4; ++i) {
#pragma unroll
            for (int r = 0; r < 4; ++r) {
                int m = bm + i * 16 + quad * 4 + r;
                float val = acc[i][j][r] + bs;
                if (MODE == 0) {
                    if (which == 0) val *= SCALE2;
                    int wl = m >> 8, t = m & 255;
                    ((short*)outp)[(size_t)which * QPLANE +
                                   ((size_t)((wl * 6 + head) * 256 + t)) * 20 + e] = bf16b(val);
                } else if (MODE == 1) {
                    int g = rev_row(m0 + m);
                    val += aux[(size_t)g * 120 + n];
                    ((float*)outp)[(size_t)(m0 + m) * 120 + n] = val;
                } else if (MODE == 2) {
                    ((short*)outp)[(size_t)m * 240 + n] = bf16b(gelu_exact(val));
                } else if (MODE == 3) {
                    size_t idx = (size_t)m * 240 + n;
                    short* o = (short*)outp;
                    o[idx] = bf16b(bf2f(o[idx]) * val);
                } else { // MODE 4: aux pre-offset by m0*120; scatter to d_out
                    int g = rev_row(m0 + m);
                    val += aux[(size_t)m * 120 + n];
                    ((float*)outp)[(size_t)g * 120 + n] = val;
                }
            }
        }
    }
}

// ---------------- MFMA flash attention, LDS-fed, zero-shuffle ----------------
// K staged to LDS in fragment order: frag (kt,f) for lane(quad,l16) at uint4
// index ((kt*2+f)*64 + quad*16 + l16)  -> consecutive-lane ds_read_b128.
// S^T = mfma(A=K[perm rows], B=Q): C regs are directly the P^T B-frag.
// No-max softmax (scale*log2e folded into q upstream); l reduced in epilogue.
template <int NK, bool MUT>
__global__ __launch_bounds__(NK, 4) void attn_flash(const short* __restrict__ qkv,
                                                    short* __restrict__ xout) {
    constexpr int NKT = NK / 32;
    constexpr int VSTR2 = NK + 4;                  // u32 stride (16B-aligned rows)
    __shared__ __align__(16) short Kf[NKT * 2 * 64 * 8];
    __shared__ __align__(16) unsigned Vt2[16 * VSTR2];
    const int b = blockIdx.x;
    int wl, hd, half;
    if (MUT) { half = b & 1; hd = (b >> 1) % 6; wl = b / 12; }
    else     { half = 0;     hd = b % 6;        wl = b / 6;  }
    const int tid  = threadIdx.x;
    const int lane = tid & 63, wave = tid >> 6;
    const int quad = lane >> 4, l16 = lane & 15;

    const size_t rb = (size_t)(wl * 6 + hd) * 256;
    const short* qpl = qkv + rb * 20;
    const short* kpl = qkv + (size_t)QPLANE + rb * 20;
    const short* vpl = qkv + 2 * (size_t)QPLANE + rb * 20;
    const int koff = MUT ? half * 128 : 0;
    const int qoff = MUT ? (1 - half) * 128 : 0;

    // ---- stage V^T (u32 dim-pairs) and K (fragment order) ----
    {
        const uint2* p = (const uint2*)(vpl + (size_t)(koff + tid) * 20);
        unsigned tmp[10];
#pragma unroll
        for (int i = 0; i < 5; ++i) ((uint2*)tmp)[i] = p[i];
#pragma unroll
        for (int i = 0; i < 10; ++i) Vt2[i * VSTR2 + tid] = tmp[i];
#pragma unroll
        for (int i = 10; i < 16; ++i) Vt2[i * VSTR2 + tid] = 0;

        int skt = tid >> 5, sf = (tid >> 4) & 1, sl = tid & 15;
        int srow = koff + skt * 32 + sf * 4 + ((sl >> 2) << 3) + (sl & 3);
        const uint2* kp = (const uint2*)(kpl + (size_t)srow * 20);
        uint2 k0 = kp[0], k1 = kp[1], k2 = kp[2], k3 = kp[3], k4 = kp[4];
        uint4* dst = (uint4*)Kf + ((skt * 2 + sf) * 64 + sl);
        dst[0]  = make_uint4(k0.x, k0.y, k1.x, k1.y);   // quad0: d0-7
        dst[16] = make_uint4(k2.x, k2.y, k3.x, k3.y);   // quad1: d8-15
        dst[32] = make_uint4(k4.x, k4.y, 0u, 0u);       // quad2: d16-23
        dst[48] = make_uint4(0u, 0u, 0u, 0u);           // quad3: pad
    }
    __syncthreads();

    // Q B-frags (pre-scaled by SCALE2 in mm<0>)
    bf16x8 bq[4];
#pragma unroll
    for (int nt = 0; nt < 4; ++nt)
        bq[nt] = load_frag20(qpl + (size_t)(qoff + wave * 64 + nt * 16 + l16) * 20, quad);

    const uint4* kfrag = (const uint4*)Kf + quad * 16 + l16;
    const unsigned sel = (l16 & 1) ? 0x07060302u : 0x05040100u;
    const unsigned* vbase0 = Vt2 + (l16 >> 1) * VSTR2;
    const unsigned* vbase1 = Vt2 + (8 + (l16 >> 1)) * VSTR2;

    f32x4 accO[4][2];
#pragma unroll
    for (int nt = 0; nt < 4; ++nt) {
        accO[nt][0] = (f32x4){0.f, 0.f, 0.f, 0.f};
        accO[nt][1] = (f32x4){0.f, 0.f, 0.f, 0.f};
    }
    float lst[4] = {0.f, 0.f, 0.f, 0.f};
    const f32x4 z4 = {0.f, 0.f, 0.f, 0.f};

#pragma unroll
    for (int kt = 0; kt < NKT; ++kt) {
        B8U ak0, ak1;
        ak0.u4 = kfrag[(kt * 2 + 0) * 64];
        ak1.u4 = kfrag[(kt * 2 + 1) * 64];
        B8U av0, av1;
        {
            uint4 va = *(const uint4*)(vbase0 + kt * 32 + quad * 8);
            uint4 vb = *(const uint4*)(vbase0 + kt * 32 + quad * 8 + 4);
            av0.u[0] = __builtin_amdgcn_perm(va.y, va.x, sel);
            av0.u[1] = __builtin_amdgcn_perm(va.w, va.z, sel);
            av0.u[2] = __builtin_amdgcn_perm(vb.y, vb.x, sel);
            av0.u[3] = __builtin_amdgcn_perm(vb.w, vb.z, sel);
            uint4 vc = *(const uint4*)(vbase1 + kt * 32 + quad * 8);
            uint4 vd = *(const uint4*)(vbase1 + kt * 32 + quad * 8 + 4);
            av1.u[0] = __builtin_amdgcn_perm(vc.y, vc.x, sel);
            av1.u[1] = __builtin_amdgcn_perm(vc.w, vc.z, sel);
            av1.u[2] = __builtin_amdgcn_perm(vd.y, vd.x, sel);
            av1.u[3] = __builtin_amdgcn_perm(vd.w, vd.z, sel);
        }
#pragma unroll
        for (int nt = 0; nt < 4; ++nt) {
            f32x4 s0 = __builtin_amdgcn_mfma_f32_16x16x32_bf16(ak0.v, bq[nt], z4, 0, 0, 0);
            f32x4 s1 = __builtin_amdgcn_mfma_f32_16x16x32_bf16(ak1.v, bq[nt], z4, 0, 0, 0);
            float p0 = __builtin_amdgcn_exp2f(s0[0]), p1 = __builtin_amdgcn_exp2f(s0[1]);
            float p2 = __builtin_amdgcn_exp2f(s0[2]), p3 = __builtin_amdgcn_exp2f(s0[3]);
            float p4 = __builtin_amdgcn_exp2f(s1[0]), p5 = __builtin_amdgcn_exp2f(s1[1]);
            float p6 = __builtin_amdgcn_exp2f(s1[2]), p7 = __builtin_amdgcn_exp2f(s1[3]);
            lst[nt] += ((p0 + p1) + (p2 + p3)) + ((p4 + p5) + (p6 + p7));
            B8U bp;   // P^T B-frag: j=0..3 <- s0 regs, j=4..7 <- s1 regs
            bp.u[0] = packbf(p0, p1);
            bp.u[1] = packbf(p2, p3);
            bp.u[2] = packbf(p4, p5);
            bp.u[3] = packbf(p6, p7);
            accO[nt][0] = __builtin_amdgcn_mfma_f32_16x16x32_bf16(av0.v, bp.v, accO[nt][0], 0, 0, 0);
            accO[nt][1] = __builtin_amdgcn_mfma_f32_16x16x32_bf16(av1.v, bp.v, accO[nt][1], 0, 0, 0);
        }
    }

    // epilogue: O^T C-layout (col l16=query, row quad*4+r=dim); reduce l over quads
#pragma unroll
    for (int nt = 0; nt < 4; ++nt) {
        float l = lst[nt];
        l += __shfl_xor(l, 16, 64);
        l += __shfl_xor(l, 32, 64);
        float inv = 1.f / l;
        int tok = (MUT ? half * 128 : 0) + wave * 64 + nt * 16 + l16;
        short* orow = xout + (size_t)(wl * 256 + tok) * 240 + (MUT ? hd * 20 : 120 + hd * 20);
        unsigned lo = packbf(accO[nt][0][0] * inv, accO[nt][0][1] * inv);
        unsigned hi2 = packbf(accO[nt][0][2] * inv, accO[nt][0][3] * inv);
        *(uint2*)(orow + quad * 4) = make_uint2(lo, hi2);
        if (quad == 0) {
            unsigned lo2 = packbf(accO[nt][1][0] * inv, accO[nt][1][1] * inv);
            unsigned hi3 = packbf(accO[nt][1][2] * inv, accO[nt][1][3] * inv);
            *(uint2*)(orow + 16) = make_uint2(lo2, hi3);
        }
    }
}

extern "C" void kernel_launch(void* const* d_in, const int* in_sizes, int n_in,
                              void* d_out, int out_size, void* d_ws, size_t ws_size,
                              hipStream_t stream) {
    const float* x          = (const float*)d_in[0];
    const float* norm1_w    = (const float*)d_in[1];
    const float* norm1_b    = (const float*)d_in[2];
    const float* qkv_self_w = (const float*)d_in[3];
    const float* qkv_self_b = (const float*)d_in[4];
    const float* qkv_mut_w  = (const float*)d_in[5];
    const float* qkv_mut_b  = (const float*)d_in[6];
    const float* proj_w     = (const float*)d_in[7];
    const float* proj_b     = (const float*)d_in[8];
    const float* norm2_w    = (const float*)d_in[9];
    const float* norm2_b    = (const float*)d_in[10];
    const float* fc11_w     = (const float*)d_in[11];
    const float* fc11_b     = (const float*)d_in[12];
    const float* fc12_w     = (const float*)d_in[13];
    const float* fc12_b     = (const float*)d_in[14];
    const float* fc2_w      = (const float*)d_in[15];
    const float* fc2_b      = (const float*)d_in[16];

    if (ws_size < 110100480u) return;

    char* wsb   = (char*)d_ws;
    short* Hb    = (short*)wsb;                  // 131072x120 bf16
    short* QKVc  = (short*)(wsb + 31457280);     // 3 planes, chunk
    short* XOUTc = (short*)(wsb + 78643200);     // 65536x240 bf16
    float* TMP   = (float*)wsb;                  // X2 copy, fp32 (MLP phase)
    short* H2c   = (short*)(wsb + 62914560);     // 65536x120 bf16
    short* HIDc  = (short*)(wsb + 78643200);     // 65536x240 bf16
    float* X2    = (float*)d_out;                // partitioned residual fp32
    float* out   = (float*)d_out;

    // 1. LN1 + window partition -> Hb (bf16)
    ln_kernel<true><<<32768, 256, 0, stream>>>(x, norm1_w, norm1_b, Hb);

    // 2. Attention phase: 2 chunks x 256 windows
    for (int c = 0; c < 2; ++c) {
        int m0 = c * CHROWS;
        const short* Ac = Hb + (size_t)m0 * 120;
        mm<0, 120, 360><<<dim3(512, 6), 256, 0, stream>>>(Ac, qkv_self_w, qkv_self_b,
                                                          QKVc, nullptr, 0);
        attn_flash<256, false><<<1536, 256, 0, stream>>>(QKVc, XOUTc);
        mm<0, 120, 360><<<dim3(512, 6), 256, 0, stream>>>(Ac, qkv_mut_w, qkv_mut_b,
                                                          QKVc, nullptr, 0);
        attn_flash<128, true><<<3072, 128, 0, stream>>>(QKVc, XOUTc);
        mm<1, 240, 120><<<dim3(512, 2), 256, 0, stream>>>(XOUTc, proj_w, proj_b,
                                                          X2, x, m0);
    }

    // 3. X2 -> TMP (frees d_out for scatter writes; residual source)
    hipMemcpyAsync(TMP, d_out, 62914560u, hipMemcpyDeviceToDevice, stream);

    // 4. MLP phase: 2 chunks x 65536 rows; fc2 scatters straight into d_out
    for (int c = 0; c < 2; ++c) {
        int m0 = c * CHROWS;
        ln_kernel<false><<<16384, 256, 0, stream>>>(TMP + (size_t)m0 * 120,
                                                    norm2_w, norm2_b, H2c);
        mm<2, 120, 240><<<dim3(512, 4), 256, 0, stream>>>(H2c, fc11_w, fc11_b,
                                                          HIDc, nullptr, 0);
        mm<3, 120, 240><<<dim3(512, 4), 256, 0, stream>>>(H2c, fc12_w, fc12_b,
                                                          HIDc, nullptr, 0);
        mm<4, 240, 120><<<dim3(512, 2), 256, 0, stream>>>(HIDc, fc2_w, fc2_b,
                                                          out, TMP + (size_t)m0 * 120, m0);
    }
}

// Round 7
// 742.956 us; speedup vs baseline: 1.2803x; 1.2803x over previous
//
#include <hip/hip_runtime.h>
#include <hip/hip_bf16.h>
#include <math.h>

// TMSA R7: R6's LDS-fed flash attention WITHOUT the occupancy bound.
// R6 lesson: __launch_bounds__(NK,4) on gfx950 caps the unified VGPR/AGPR
// file at 128 -> with 64 AGPRs live the arch side fell to 64 and the kt-loop
// spilled to scratch (WRITE_SIZE 24MB->233MB). This kernel needs ~150 VGPRs;
// let the compiler have them (R5 compiled 156, zero spill).
//
// ws (bytes), guard 110,100,480:
//   attn phase: Hb bf16 [0,31457280) | QKVc bf16 [31457280,78643200)
//               XOUTc bf16 [78643200,110100480)
//   mlp  phase: TMP fp32 [0,62914560) (d2d copy of X2) |
//               H2c bf16 [62914560,78643200) | HIDc bf16 [78643200,110100480)

typedef __attribute__((ext_vector_type(8))) short bf16x8;
typedef __attribute__((ext_vector_type(4))) float f32x4;

#define SCALE2 (0.22360679774997896f * 1.44269504088896340f)  // d^-0.5 * log2(e)
#define CHROWS 65536
#define QPLANE 7864320u   // 65536*120 elems per q/k/v plane (chunk)

union B8U { bf16x8 v; uint4 u4; uint2 u2[2]; unsigned u[4]; short s[8]; };

__device__ __forceinline__ short bf16b(float f) {
    __hip_bfloat16 h = __float2bfloat16(f);
    return *reinterpret_cast<short*>(&h);
}
__device__ __forceinline__ float bf2f(short s) {
    return __uint_as_float(((unsigned)(unsigned short)s) << 16);
}
__device__ __forceinline__ unsigned packbf(float a, float b) {
    return (unsigned)(unsigned short)bf16b(a) |
           ((unsigned)(unsigned short)bf16b(b) << 16);
}

// partitioned row r -> global row g
__device__ __forceinline__ int rev_row(int r) {
    int w = r >> 8, t = r & 255;
    int w8 = w & 7, h8 = (w >> 3) & 7, d2 = (w >> 6) & 1, n2 = w >> 7;
    int www = t & 7, hh = (t >> 3) & 7, dd = (t >> 6) & 1, nn = t >> 7;
    int n = n2 * 2 + nn, d = d2 * 2 + dd;
    int Hc = h8 * 8 + hh, Wc = w8 * 8 + www;
    return ((n * 4 + d) << 12) + (Hc << 6) + Wc;
}
// global row g -> partitioned row
__device__ __forceinline__ int part_row(int g) {
    int ww = g & 63, hh = (g >> 6) & 63, d = (g >> 12) & 3, n = g >> 14;
    int w = ((n >> 1) * 2 + (d >> 1)) * 64 + ((hh >> 3) << 3) + (ww >> 3);
    int t = (((n & 1) * 2 + (d & 1)) << 6) + ((hh & 7) << 3) + (ww & 7);
    return (w << 8) + t;
}
__device__ __forceinline__ float gelu_exact(float x) {
    return 0.5f * x * (1.0f + erff(x * 0.70710678118654752f));
}

// load B-frag from a 20-elem bf16 row (stride 20), k = quad*8..+7, zero-padded.
__device__ __forceinline__ bf16x8 load_frag20(const short* row, int quad) {
    B8U r;
    const uint2* p = (const uint2*)(row + quad * 8);
    r.u2[0] = p[0]; r.u2[1] = p[1];
    if (quad == 2) { r.u[2] = 0; r.u[3] = 0; }
    else if (quad == 3) { r.u[0] = r.u[1] = r.u[2] = r.u[3] = 0; }
    return r.v;
}

// ---------------- LayerNorm (C=120) fp32 in -> bf16 out ---------------------
template <bool REMAP>
__global__ __launch_bounds__(256) void ln_kernel(const float* __restrict__ in,
                                                 const float* __restrict__ w,
                                                 const float* __restrict__ b,
                                                 short* __restrict__ out) {
    int row  = blockIdx.x * 4 + (threadIdx.x >> 6);
    int lane = threadIdx.x & 63;
    const float* xr = in + (size_t)row * 120;
    float2 v = make_float2(0.f, 0.f);
    if (lane < 60) v = *(const float2*)(xr + lane * 2);
    float s = v.x + v.y;
#pragma unroll
    for (int off = 32; off; off >>= 1) s += __shfl_down(s, off, 64);
    s = __shfl(s, 0, 64);
    float mean = s * (1.f / 120.f);
    float dx = v.x - mean, dy = v.y - mean;
    float q = (lane < 60) ? (dx * dx + dy * dy) : 0.f;
#pragma unroll
    for (int off = 32; off; off >>= 1) q += __shfl_down(q, off, 64);
    q = __shfl(q, 0, 64);
    float rstd = rsqrtf(q * (1.f / 120.f) + 1e-5f);
    int orow = REMAP ? part_row(row) : row;
    if (lane < 60) {
        float2 wv = *(const float2*)(w + lane * 2);
        float2 bv = *(const float2*)(b + lane * 2);
        unsigned u = packbf(dx * rstd * wv.x + bv.x, dy * rstd * wv.y + bv.y);
        *(unsigned*)(out + (size_t)orow * 120 + lane * 2) = u;
    }
}

// ------------- MFMA GEMM: out = A(M x K, bf16) @ W(N x K, fp32)^T + bias ----
// MODE: 0 QKV scatter (q pre-scaled by SCALE2) | 1 proj(+x res -> X2 fp32)
//       2 gelu bf16 | 3 multiply-into bf16 | 4 fc2(+TMP res -> d_out @rev_row)
template <int MODE, int K, int N>
__global__ __launch_bounds__(256) void mm(const short* __restrict__ A,
                                          const float* __restrict__ W,
                                          const float* __restrict__ bias,
                                          void* __restrict__ outp,
                                          const float* __restrict__ aux,
                                          int m0) {
    const int lane = threadIdx.x & 63, wave = threadIdx.x >> 6;
    const int quad = lane >> 4, l16 = lane & 15;
    const int bm = blockIdx.x * 128 + (wave >> 1) * 64;
    const int bn = blockIdx.y * 64 + (wave & 1) * 32;

    f32x4 acc[4][2];
#pragma unroll
    for (int i = 0; i < 4; ++i)
#pragma unroll
        for (int j = 0; j < 2; ++j) acc[i][j] = (f32x4){0.f, 0.f, 0.f, 0.f};

    const short* Ar[4];
#pragma unroll
    for (int i = 0; i < 4; ++i) Ar[i] = A + (size_t)(bm + i * 16 + l16) * K;
    const int n0 = bn + l16, n1 = bn + 16 + l16;
    const int nc0 = n0 < N ? n0 : N - 1;
    const int nc1 = n1 < N ? n1 : N - 1;
    const float* W0 = W + (size_t)nc0 * K;
    const float* W1 = W + (size_t)nc1 * K;

    const int KT = (K + 31) / 32;
#pragma unroll
    for (int kt = 0; kt < KT; ++kt) {
        int kk = kt * 32 + quad * 8;
        bool kok = kk < K;
        int kc = kok ? kk : 0;
        bf16x8 a[4], b0v, b1v;
#pragma unroll
        for (int i = 0; i < 4; ++i) a[i] = *(const bf16x8*)(Ar[i] + kc);
        {
            f32x4 w0 = *(const f32x4*)(W0 + kc);
            f32x4 w1 = *(const f32x4*)(W0 + kc + 4);
            b0v = (bf16x8){bf16b(w0.x), bf16b(w0.y), bf16b(w0.z), bf16b(w0.w),
                           bf16b(w1.x), bf16b(w1.y), bf16b(w1.z), bf16b(w1.w)};
            f32x4 w2 = *(const f32x4*)(W1 + kc);
            f32x4 w3 = *(const f32x4*)(W1 + kc + 4);
            b1v = (bf16x8){bf16b(w2.x), bf16b(w2.y), bf16b(w2.z), bf16b(w2.w),
                           bf16b(w3.x), bf16b(w3.y), bf16b(w3.z), bf16b(w3.w)};
        }
        if (!kok) {
            bf16x8 zz = {0, 0, 0, 0, 0, 0, 0, 0};
            a[0] = a[1] = a[2] = a[3] = b0v = b1v = zz;
        }
#pragma unroll
        for (int i = 0; i < 4; ++i) {
            acc[i][0] = __builtin_amdgcn_mfma_f32_16x16x32_bf16(a[i], b0v, acc[i][0], 0, 0, 0);
            acc[i][1] = __builtin_amdgcn_mfma_f32_16x16x32_bf16(a[i], b1v, acc[i][1], 0, 0, 0);
        }
    }

#pragma unroll
    for (int j = 0; j < 2; ++j) {
        const int n = j ? n1 : n0;
        if (n >= N) continue;
        const float bs = bias[n];
        int which = 0, head = 0, e = 0;
        if (MODE == 0) { which = n / 120; int hn = n % 120; head = hn / 20; e = hn % 20; }
#pragma unroll
        for (int i = 0; i < 4; ++i) {
#pragma unroll
            for (int r = 0; r < 4; ++r) {
                int m = bm + i * 16 + quad * 4 + r;
                float val = acc[i][j][r] + bs;
                if (MODE == 0) {
                    if (which == 0) val *= SCALE2;
                    int wl = m >> 8, t = m & 255;
                    ((short*)outp)[(size_t)which * QPLANE +
                                   ((size_t)((wl * 6 + head) * 256 + t)) * 20 + e] = bf16b(val);
                } else if (MODE == 1) {
                    int g = rev_row(m0 + m);
                    val += aux[(size_t)g * 120 + n];
                    ((float*)outp)[(size_t)(m0 + m) * 120 + n] = val;
                } else if (MODE == 2) {
                    ((short*)outp)[(size_t)m * 240 + n] = bf16b(gelu_exact(val));
                } else if (MODE == 3) {
                    size_t idx = (size_t)m * 240 + n;
                    short* o = (short*)outp;
                    o[idx] = bf16b(bf2f(o[idx]) * val);
                } else { // MODE 4: aux pre-offset by m0*120; scatter to d_out
                    int g = rev_row(m0 + m);
                    val += aux[(size_t)m * 120 + n];
                    ((float*)outp)[(size_t)g * 120 + n] = val;
                }
            }
        }
    }
}

// ---------------- MFMA flash attention, LDS-fed, zero-shuffle ----------------
// K staged to LDS in fragment order: frag (kt,f) for lane(quad,l16) at uint4
// index ((kt*2+f)*64 + quad*16 + l16)  -> consecutive-lane ds_read_b128.
// S^T = mfma(A=K[perm rows], B=Q): C regs are directly the P^T B-frag.
// No-max softmax (scale*log2e folded into q upstream); l reduced in epilogue.
// NOTE: no occupancy bound — needs ~150 VGPRs; capping spills (R6: 233MB scratch).
template <int NK, bool MUT>
__global__ __launch_bounds__(NK) void attn_flash(const short* __restrict__ qkv,
                                                 short* __restrict__ xout) {
    constexpr int NKT = NK / 32;
    constexpr int VSTR2 = NK + 4;                  // u32 stride (16B-aligned rows)
    __shared__ __align__(16) short Kf[NKT * 2 * 64 * 8];
    __shared__ __align__(16) unsigned Vt2[16 * VSTR2];
    const int b = blockIdx.x;
    int wl, hd, half;
    if (MUT) { half = b & 1; hd = (b >> 1) % 6; wl = b / 12; }
    else     { half = 0;     hd = b % 6;        wl = b / 6;  }
    const int tid  = threadIdx.x;
    const int lane = tid & 63, wave = tid >> 6;
    const int quad = lane >> 4, l16 = lane & 15;

    const size_t rb = (size_t)(wl * 6 + hd) * 256;
    const short* qpl = qkv + rb * 20;
    const short* kpl = qkv + (size_t)QPLANE + rb * 20;
    const short* vpl = qkv + 2 * (size_t)QPLANE + rb * 20;
    const int koff = MUT ? half * 128 : 0;
    const int qoff = MUT ? (1 - half) * 128 : 0;

    // ---- stage V^T (u32 dim-pairs) and K (fragment order) ----
    {
        const uint2* p = (const uint2*)(vpl + (size_t)(koff + tid) * 20);
        unsigned tmp[10];
#pragma unroll
        for (int i = 0; i < 5; ++i) ((uint2*)tmp)[i] = p[i];
#pragma unroll
        for (int i = 0; i < 10; ++i) Vt2[i * VSTR2 + tid] = tmp[i];
#pragma unroll
        for (int i = 10; i < 16; ++i) Vt2[i * VSTR2 + tid] = 0;

        int skt = tid >> 5, sf = (tid >> 4) & 1, sl = tid & 15;
        int srow = koff + skt * 32 + sf * 4 + ((sl >> 2) << 3) + (sl & 3);
        const uint2* kp = (const uint2*)(kpl + (size_t)srow * 20);
        uint2 k0 = kp[0], k1 = kp[1], k2 = kp[2], k3 = kp[3], k4 = kp[4];
        uint4* dst = (uint4*)Kf + ((skt * 2 + sf) * 64 + sl);
        dst[0]  = make_uint4(k0.x, k0.y, k1.x, k1.y);   // quad0: d0-7
        dst[16] = make_uint4(k2.x, k2.y, k3.x, k3.y);   // quad1: d8-15
        dst[32] = make_uint4(k4.x, k4.y, 0u, 0u);       // quad2: d16-23
        dst[48] = make_uint4(0u, 0u, 0u, 0u);           // quad3: pad
    }
    __syncthreads();

    // Q B-frags (pre-scaled by SCALE2 in mm<0>)
    bf16x8 bq[4];
#pragma unroll
    for (int nt = 0; nt < 4; ++nt)
        bq[nt] = load_frag20(qpl + (size_t)(qoff + wave * 64 + nt * 16 + l16) * 20, quad);

    const uint4* kfrag = (const uint4*)Kf + quad * 16 + l16;
    const unsigned sel = (l16 & 1) ? 0x07060302u : 0x05040100u;
    const unsigned* vbase0 = Vt2 + (l16 >> 1) * VSTR2;
    const unsigned* vbase1 = Vt2 + (8 + (l16 >> 1)) * VSTR2;

    f32x4 accO[4][2];
#pragma unroll
    for (int nt = 0; nt < 4; ++nt) {
        accO[nt][0] = (f32x4){0.f, 0.f, 0.f, 0.f};
        accO[nt][1] = (f32x4){0.f, 0.f, 0.f, 0.f};
    }
    float lst[4] = {0.f, 0.f, 0.f, 0.f};
    const f32x4 z4 = {0.f, 0.f, 0.f, 0.f};

#pragma unroll
    for (int kt = 0; kt < NKT; ++kt) {
        B8U ak0, ak1;
        ak0.u4 = kfrag[(kt * 2 + 0) * 64];
        ak1.u4 = kfrag[(kt * 2 + 1) * 64];
        B8U av0, av1;
        {
            uint4 va = *(const uint4*)(vbase0 + kt * 32 + quad * 8);
            uint4 vb = *(const uint4*)(vbase0 + kt * 32 + quad * 8 + 4);
            av0.u[0] = __builtin_amdgcn_perm(va.y, va.x, sel);
            av0.u[1] = __builtin_amdgcn_perm(va.w, va.z, sel);
            av0.u[2] = __builtin_amdgcn_perm(vb.y, vb.x, sel);
            av0.u[3] = __builtin_amdgcn_perm(vb.w, vb.z, sel);
            uint4 vc = *(const uint4*)(vbase1 + kt * 32 + quad * 8);
            uint4 vd = *(const uint4*)(vbase1 + kt * 32 + quad * 8 + 4);
            av1.u[0] = __builtin_amdgcn_perm(vc.y, vc.x, sel);
            av1.u[1] = __builtin_amdgcn_perm(vc.w, vc.z, sel);
            av1.u[2] = __builtin_amdgcn_perm(vd.y, vd.x, sel);
            av1.u[3] = __builtin_amdgcn_perm(vd.w, vd.z, sel);
        }
#pragma unroll
        for (int nt = 0; nt < 4; ++nt) {
            f32x4 s0 = __builtin_amdgcn_mfma_f32_16x16x32_bf16(ak0.v, bq[nt], z4, 0, 0, 0);
            f32x4 s1 = __builtin_amdgcn_mfma_f32_16x16x32_bf16(ak1.v, bq[nt], z4, 0, 0, 0);
            float p0 = __builtin_amdgcn_exp2f(s0[0]), p1 = __builtin_amdgcn_exp2f(s0[1]);
            float p2 = __builtin_amdgcn_exp2f(s0[2]), p3 = __builtin_amdgcn_exp2f(s0[3]);
            float p4 = __builtin_amdgcn_exp2f(s1[0]), p5 = __builtin_amdgcn_exp2f(s1[1]);
            float p6 = __builtin_amdgcn_exp2f(s1[2]), p7 = __builtin_amdgcn_exp2f(s1[3]);
            lst[nt] += ((p0 + p1) + (p2 + p3)) + ((p4 + p5) + (p6 + p7));
            B8U bp;   // P^T B-frag: j=0..3 <- s0 regs, j=4..7 <- s1 regs
            bp.u[0] = packbf(p0, p1);
            bp.u[1] = packbf(p2, p3);
            bp.u[2] = packbf(p4, p5);
            bp.u[3] = packbf(p6, p7);
            accO[nt][0] = __builtin_amdgcn_mfma_f32_16x16x32_bf16(av0.v, bp.v, accO[nt][0], 0, 0, 0);
            accO[nt][1] = __builtin_amdgcn_mfma_f32_16x16x32_bf16(av1.v, bp.v, accO[nt][1], 0, 0, 0);
        }
    }

    // epilogue: O^T C-layout (col l16=query, row quad*4+r=dim); reduce l over quads
#pragma unroll
    for (int nt = 0; nt < 4; ++nt) {
        float l = lst[nt];
        l += __shfl_xor(l, 16, 64);
        l += __shfl_xor(l, 32, 64);
        float inv = 1.f / l;
        int tok = (MUT ? half * 128 : 0) + wave * 64 + nt * 16 + l16;
        short* orow = xout + (size_t)(wl * 256 + tok) * 240 + (MUT ? hd * 20 : 120 + hd * 20);
        unsigned lo = packbf(accO[nt][0][0] * inv, accO[nt][0][1] * inv);
        unsigned hi2 = packbf(accO[nt][0][2] * inv, accO[nt][0][3] * inv);
        *(uint2*)(orow + quad * 4) = make_uint2(lo, hi2);
        if (quad == 0) {
            unsigned lo2 = packbf(accO[nt][1][0] * inv, accO[nt][1][1] * inv);
            unsigned hi3 = packbf(accO[nt][1][2] * inv, accO[nt][1][3] * inv);
            *(uint2*)(orow + 16) = make_uint2(lo2, hi3);
        }
    }
}

extern "C" void kernel_launch(void* const* d_in, const int* in_sizes, int n_in,
                              void* d_out, int out_size, void* d_ws, size_t ws_size,
                              hipStream_t stream) {
    const float* x          = (const float*)d_in[0];
    const float* norm1_w    = (const float*)d_in[1];
    const float* norm1_b    = (const float*)d_in[2];
    const float* qkv_self_w = (const float*)d_in[3];
    const float* qkv_self_b = (const float*)d_in[4];
    const float* qkv_mut_w  = (const float*)d_in[5];
    const float* qkv_mut_b  = (const float*)d_in[6];
    const float* proj_w     = (const float*)d_in[7];
    const float* proj_b     = (const float*)d_in[8];
    const float* norm2_w    = (const float*)d_in[9];
    const float* norm2_b    = (const float*)d_in[10];
    const float* fc11_w     = (const float*)d_in[11];
    const float* fc11_b     = (const float*)d_in[12];
    const float* fc12_w     = (const float*)d_in[13];
    const float* fc12_b     = (const float*)d_in[14];
    const float* fc2_w      = (const float*)d_in[15];
    const float* fc2_b      = (const float*)d_in[16];

    if (ws_size < 110100480u) return;

    char* wsb   = (char*)d_ws;
    short* Hb    = (short*)wsb;                  // 131072x120 bf16
    short* QKVc  = (short*)(wsb + 31457280);     // 3 planes, chunk
    short* XOUTc = (short*)(wsb + 78643200);     // 65536x240 bf16
    float* TMP   = (float*)wsb;                  // X2 copy, fp32 (MLP phase)
    short* H2c   = (short*)(wsb + 62914560);     // 65536x120 bf16
    short* HIDc  = (short*)(wsb + 78643200);     // 65536x240 bf16
    float* X2    = (float*)d_out;                // partitioned residual fp32
    float* out   = (float*)d_out;

    // 1. LN1 + window partition -> Hb (bf16)
    ln_kernel<true><<<32768, 256, 0, stream>>>(x, norm1_w, norm1_b, Hb);

    // 2. Attention phase: 2 chunks x 256 windows
    for (int c = 0; c < 2; ++c) {
        int m0 = c * CHROWS;
        const short* Ac = Hb + (size_t)m0 * 120;
        mm<0, 120, 360><<<dim3(512, 6), 256, 0, stream>>>(Ac, qkv_self_w, qkv_self_b,
                                                          QKVc, nullptr, 0);
        attn_flash<256, false><<<1536, 256, 0, stream>>>(QKVc, XOUTc);
        mm<0, 120, 360><<<dim3(512, 6), 256, 0, stream>>>(Ac, qkv_mut_w, qkv_mut_b,
                                                          QKVc, nullptr, 0);
        attn_flash<128, true><<<3072, 128, 0, stream>>>(QKVc, XOUTc);
        mm<1, 240, 120><<<dim3(512, 2), 256, 0, stream>>>(XOUTc, proj_w, proj_b,
                                                          X2, x, m0);
    }

    // 3. X2 -> TMP (frees d_out for scatter writes; residual source)
    hipMemcpyAsync(TMP, d_out, 62914560u, hipMemcpyDeviceToDevice, stream);

    // 4. MLP phase: 2 chunks x 65536 rows; fc2 scatters straight into d_out
    for (int c = 0; c < 2; ++c) {
        int m0 = c * CHROWS;
        ln_kernel<false><<<16384, 256, 0, stream>>>(TMP + (size_t)m0 * 120,
                                                    norm2_w, norm2_b, H2c);
        mm<2, 120, 240><<<dim3(512, 4), 256, 0, stream>>>(H2c, fc11_w, fc11_b,
                                                          HIDc, nullptr, 0);
        mm<3, 120, 240><<<dim3(512, 4), 256, 0, stream>>>(H2c, fc12_w, fc12_b,
                                                          HIDc, nullptr, 0);
        mm<4, 240, 120><<<dim3(512, 2), 256, 0, stream>>>(HIDc, fc2_w, fc2_b,
                                                          out, TMP + (size_t)m0 * 120, m0);
    }
}